// Round 1
// baseline (2404.304 us; speedup 1.0000x reference)
//
#include <hip/hip_runtime.h>

// Problem constants (from reference)
constexpr int T_FRAMES = 96;
constexpr int HH = 720;
constexpr int WW = 1280;
constexpr int HW = HH * WW;            // 921600
constexpr int N_NOISE = 10;

// Tiling: each thread handles PIX consecutive pixels for a chunk of TPC frames,
// carrying prev-frame values in registers so each tensor element is read once.
constexpr int TC  = 4;                 // number of t-chunks
constexpr int TPC = T_FRAMES / TC;     // 24 frames per chunk
constexpr int PIX = 4;                 // pixels per thread (float4)
constexpr int BLOCK = 256;

// ---------------------------------------------------------------------------
// Noise-dtype detection: the harness may hand us the jnp.bool_ arrays as raw
// uint8, widened int32, or widened float32. Inspect byte patterns of the first
// 1 MiB (safe: smallest possible buffer is 9.2 MB of uint8).
//   flag = 0 -> int32   (nonzero bytes only at i%4==0)
//   flag = 1 -> uint8   (nonzero bytes at all byte positions)
//   flag = 2 -> float32 (1.0f = 00 00 80 3f: nonzero bytes only at i%4 in {2,3})
// ---------------------------------------------------------------------------
__global__ void detect_noise_dtype(const unsigned char* __restrict__ noise,
                                   int* __restrict__ flag) {
    __shared__ int sA, sB;
    if (threadIdx.x == 0) { sA = 0; sB = 0; }
    __syncthreads();
    int a = 0, b = 0;
    const int NB = 1 << 20;
    for (int i = threadIdx.x; i < NB; i += blockDim.x) {
        if (noise[i]) {
            if ((i & 3) == 0) a++;
            else b++;
        }
    }
    if (a) atomicAdd(&sA, a);
    if (b) atomicAdd(&sB, b);
    __syncthreads();
    if (threadIdx.x == 0) {
        *flag = (sB == 0) ? 0 : ((sA == 0) ? 2 : 1);
    }
}

template <int FLAG>
__device__ __forceinline__ uint4 load_noise4(const void* __restrict__ p, int idx) {
    if (FLAG == 1) {
        const uchar4 v = *reinterpret_cast<const uchar4*>(
            reinterpret_cast<const unsigned char*>(p) + idx);
        return make_uint4(v.x, v.y, v.z, v.w);
    } else if (FLAG == 0) {
        const int4 v = *reinterpret_cast<const int4*>(
            reinterpret_cast<const int*>(p) + idx);
        return make_uint4(v.x != 0, v.y != 0, v.z != 0, v.w != 0);
    } else {
        const float4 v = *reinterpret_cast<const float4*>(
            reinterpret_cast<const float*>(p) + idx);
        return make_uint4(v.x != 0.f, v.y != 0.f, v.z != 0.f, v.w != 0.f);
    }
}

__device__ __forceinline__ float classify(float cur, float prev,
                                          unsigned on, unsigned off) {
    const float d = cur - prev;
    float o = (d == 0.f) ? 127.f : (d > 0.f ? 255.f : 0.f);
    if (on)  o = 255.f;   // on-noise forces 255 ...
    if (off) o = 0.f;     // ... but off-noise wins (matches reference nesting)
    return o;
}

template <int FLAG>
__device__ void neuro_body(const float* __restrict__ tensor,
                           const float* __restrict__ state,
                           const void* __restrict__ on_noise,
                           const void* __restrict__ off_noise,
                           float* __restrict__ out) {
    const int p = (blockIdx.x * BLOCK + threadIdx.x) * PIX;
    if (p >= HW) return;
    const int t0 = blockIdx.y * TPC;

    float4 prev;
    if (t0 == 0) {
        prev = *reinterpret_cast<const float4*>(state + p);        // zeros in practice
    } else {
        prev = *reinterpret_cast<const float4*>(tensor + (t0 - 1) * HW + p);
    }

#pragma unroll 4
    for (int t = t0; t < t0 + TPC; ++t) {
        const float4 cur = *reinterpret_cast<const float4*>(tensor + t * HW + p);
        const int ni = (t + 1) % N_NOISE;                          // cnt % N_NOISE
        const uint4 n_on  = load_noise4<FLAG>(on_noise,  ni * HW + p);
        const uint4 n_off = load_noise4<FLAG>(off_noise, ni * HW + p);

        float4 o;
        o.x = classify(cur.x, prev.x, n_on.x, n_off.x);
        o.y = classify(cur.y, prev.y, n_on.y, n_off.y);
        o.z = classify(cur.z, prev.z, n_on.z, n_off.z);
        o.w = classify(cur.w, prev.w, n_on.w, n_off.w);

        *reinterpret_cast<float4*>(out + t * HW + p) = o;
        prev = cur;
    }
}

__global__ __launch_bounds__(BLOCK)
void neuro_kernel(const float* __restrict__ tensor,
                  const float* __restrict__ state,
                  const void* __restrict__ on_noise,
                  const void* __restrict__ off_noise,
                  float* __restrict__ out,
                  const int* __restrict__ flag_p) {
    const int flag = *flag_p;          // wave-uniform branch, L2-cached read
    if (flag == 1)      neuro_body<1>(tensor, state, on_noise, off_noise, out);
    else if (flag == 0) neuro_body<0>(tensor, state, on_noise, off_noise, out);
    else                neuro_body<2>(tensor, state, on_noise, off_noise, out);
}

extern "C" void kernel_launch(void* const* d_in, const int* in_sizes, int n_in,
                              void* d_out, int out_size, void* d_ws, size_t ws_size,
                              hipStream_t stream) {
    const float* tensor   = (const float*)d_in[0];   // (T,H,W) f32
    const float* state    = (const float*)d_in[1];   // (H,W) f32
    // d_in[2] = timesurface (H,W) f32 — provably unused (refractory is a no-op)
    const void*  on_noise  = d_in[3];                // (N_NOISE,H,W) bool
    const void*  off_noise = d_in[4];                // (N_NOISE,H,W) bool
    float* out = (float*)d_out;                      // (T,H,W) f32
    int* flag = (int*)d_ws;

    detect_noise_dtype<<<1, BLOCK, 0, stream>>>(
        (const unsigned char*)on_noise, flag);

    dim3 grid(HW / PIX / BLOCK, TC);                 // (900, 4)
    neuro_kernel<<<grid, BLOCK, 0, stream>>>(
        tensor, state, on_noise, off_noise, out, flag);
}

// Round 2
// 707.261 us; speedup vs baseline: 3.3995x; 3.3995x over previous
//
#include <hip/hip_runtime.h>

// Problem constants (from reference)
constexpr int T_FRAMES = 96;
constexpr int HH = 720;
constexpr int WW = 1280;
constexpr int HW = HH * WW;            // 921600
constexpr int N_NOISE = 10;

// Tiling: each thread handles PIX consecutive pixels for a chunk of TPC frames,
// carrying prev-frame values in registers so each tensor element is read once.
constexpr int TC  = 4;                 // number of t-chunks
constexpr int TPC = T_FRAMES / TC;     // 24 frames per chunk
constexpr int PIX = 4;                 // pixels per thread (float4)
constexpr int BLOCK = 256;

// ---------------------------------------------------------------------------
// Noise-dtype detection (fast, parallel): sample the first 256 KiB of on_noise
// with 64 blocks x 256 threads x one uint4 load. P_NOISE=0.001 guarantees
// hundreds (uint8) / dozens (f32/i32) of nonzero elements in the sample.
// Count nonzero bytes at word-position 0 (a) vs positions 1..3 (b):
//   int32 0/1  : nonzero only at byte 0      -> b == 0            -> flag 0
//   float32 1.0: bytes 00 00 80 3f, byte0==0 -> a == 0            -> flag 2
//   uint8 0/1  : nonzero at all positions    -> a != 0 && b != 0  -> flag 1
// Counters live in d_ws[0..1] (zeroed via hipMemsetAsync); the main kernel
// derives the flag from them (wave-uniform branch).
// ---------------------------------------------------------------------------
constexpr int DET_BLOCKS = 64;         // 64*256*16B = 256 KiB sampled

__global__ __launch_bounds__(BLOCK)
void detect_noise_dtype(const uint4* __restrict__ noise,
                        unsigned int* __restrict__ counters) {
    const int i = blockIdx.x * BLOCK + threadIdx.x;
    const uint4 v = noise[i];
    unsigned a = 0, b = 0;
    const unsigned w[4] = {v.x, v.y, v.z, v.w};
#pragma unroll
    for (int k = 0; k < 4; ++k) {
        a += ((w[k] & 0x000000ffu) != 0);
        b += ((w[k] & 0x0000ff00u) != 0);
        b += ((w[k] & 0x00ff0000u) != 0);
        b += ((w[k] & 0xff000000u) != 0);
    }
    if (a) atomicAdd(&counters[0], a);
    if (b) atomicAdd(&counters[1], b);
}

template <int FLAG>
__device__ __forceinline__ uint4 load_noise4(const void* __restrict__ p, int idx) {
    if (FLAG == 1) {
        const uchar4 v = *reinterpret_cast<const uchar4*>(
            reinterpret_cast<const unsigned char*>(p) + idx);
        return make_uint4(v.x, v.y, v.z, v.w);
    } else if (FLAG == 0) {
        const int4 v = *reinterpret_cast<const int4*>(
            reinterpret_cast<const int*>(p) + idx);
        return make_uint4(v.x != 0, v.y != 0, v.z != 0, v.w != 0);
    } else {
        const float4 v = *reinterpret_cast<const float4*>(
            reinterpret_cast<const float*>(p) + idx);
        return make_uint4(v.x != 0.f, v.y != 0.f, v.z != 0.f, v.w != 0.f);
    }
}

__device__ __forceinline__ float classify(float cur, float prev,
                                          unsigned on, unsigned off) {
    const float d = cur - prev;
    float o = (d == 0.f) ? 127.f : (d > 0.f ? 255.f : 0.f);
    if (on)  o = 255.f;   // on-noise forces 255 ...
    if (off) o = 0.f;     // ... but off-noise wins (matches reference nesting)
    return o;
}

template <int FLAG>
__device__ void neuro_body(const float* __restrict__ tensor,
                           const float* __restrict__ state,
                           const void* __restrict__ on_noise,
                           const void* __restrict__ off_noise,
                           float* __restrict__ out) {
    const int p = (blockIdx.x * BLOCK + threadIdx.x) * PIX;
    if (p >= HW) return;
    const int t0 = blockIdx.y * TPC;

    float4 prev;
    if (t0 == 0) {
        prev = *reinterpret_cast<const float4*>(state + p);        // zeros in practice
    } else {
        prev = *reinterpret_cast<const float4*>(tensor + (t0 - 1) * HW + p);
    }

#pragma unroll 4
    for (int t = t0; t < t0 + TPC; ++t) {
        const float4 cur = *reinterpret_cast<const float4*>(tensor + t * HW + p);
        const int ni = (t + 1) % N_NOISE;                          // cnt % N_NOISE
        const uint4 n_on  = load_noise4<FLAG>(on_noise,  ni * HW + p);
        const uint4 n_off = load_noise4<FLAG>(off_noise, ni * HW + p);

        float4 o;
        o.x = classify(cur.x, prev.x, n_on.x, n_off.x);
        o.y = classify(cur.y, prev.y, n_on.y, n_off.y);
        o.z = classify(cur.z, prev.z, n_on.z, n_off.z);
        o.w = classify(cur.w, prev.w, n_on.w, n_off.w);

        *reinterpret_cast<float4*>(out + t * HW + p) = o;
        prev = cur;
    }
}

__global__ __launch_bounds__(BLOCK)
void neuro_kernel(const float* __restrict__ tensor,
                  const float* __restrict__ state,
                  const void* __restrict__ on_noise,
                  const void* __restrict__ off_noise,
                  float* __restrict__ out,
                  const unsigned int* __restrict__ counters) {
    const unsigned a = counters[0], b = counters[1];
    const int flag = (b == 0u) ? 0 : ((a == 0u) ? 2 : 1);   // wave-uniform
    if (flag == 1)      neuro_body<1>(tensor, state, on_noise, off_noise, out);
    else if (flag == 0) neuro_body<0>(tensor, state, on_noise, off_noise, out);
    else                neuro_body<2>(tensor, state, on_noise, off_noise, out);
}

extern "C" void kernel_launch(void* const* d_in, const int* in_sizes, int n_in,
                              void* d_out, int out_size, void* d_ws, size_t ws_size,
                              hipStream_t stream) {
    const float* tensor   = (const float*)d_in[0];   // (T,H,W) f32
    const float* state    = (const float*)d_in[1];   // (H,W) f32
    // d_in[2] = timesurface (H,W) f32 — provably unused (refractory is a no-op)
    const void*  on_noise  = d_in[3];                // (N_NOISE,H,W) bool
    const void*  off_noise = d_in[4];                // (N_NOISE,H,W) bool
    float* out = (float*)d_out;                      // (T,H,W) f32
    unsigned int* counters = (unsigned int*)d_ws;    // [a, b]

    hipMemsetAsync(counters, 0, 2 * sizeof(unsigned int), stream);

    detect_noise_dtype<<<DET_BLOCKS, BLOCK, 0, stream>>>(
        (const uint4*)on_noise, counters);

    dim3 grid(HW / PIX / BLOCK, TC);                 // (900, 4)
    neuro_kernel<<<grid, BLOCK, 0, stream>>>(
        tensor, state, on_noise, off_noise, out, counters);
}

// Round 3
// 609.651 us; speedup vs baseline: 3.9437x; 1.1601x over previous
//
#include <hip/hip_runtime.h>

// Problem constants (from reference)
constexpr int T_FRAMES = 96;
constexpr int HH = 720;
constexpr int WW = 1280;
constexpr int HW = HH * WW;            // 921600
constexpr int N_NOISE = 10;

constexpr int PIX = 4;                 // pixels per thread (float4)
constexpr int BLOCK = 64;              // 1 wave per block -> fine-grained balance
constexpr int NBLOCKS = HW / PIX / BLOCK;  // 3600 blocks, ~14.06 per CU

typedef float f4 __attribute__((ext_vector_type(4)));

// ---------------------------------------------------------------------------
// Noise-dtype detection (parallel, ~5 us): sample first 256 KiB of on_noise.
// Count nonzero bytes at word-position 0 (a) vs positions 1..3 (b):
//   int32 0/1  : nonzero only at byte 0      -> b == 0            -> flag 0
//   float32 1.0: bytes 00 00 80 3f, byte0==0 -> a == 0            -> flag 2
//   uint8 0/1  : nonzero at all positions    -> a != 0 && b != 0  -> flag 1
// P_NOISE=0.001 -> sample has ~260 (u8) / ~65 (widened) nonzero elements.
// ---------------------------------------------------------------------------
constexpr int DET_BLOCKS = 64;         // 64*256*16B = 256 KiB sampled

__global__ __launch_bounds__(256)
void detect_noise_dtype(const uint4* __restrict__ noise,
                        unsigned int* __restrict__ counters) {
    const int i = blockIdx.x * 256 + threadIdx.x;
    const uint4 v = noise[i];
    unsigned a = 0, b = 0;
    const unsigned w[4] = {v.x, v.y, v.z, v.w};
#pragma unroll
    for (int k = 0; k < 4; ++k) {
        a += ((w[k] & 0x000000ffu) != 0);
        b += ((w[k] & 0x0000ff00u) != 0);
        b += ((w[k] & 0x00ff0000u) != 0);
        b += ((w[k] & 0xff000000u) != 0);
    }
    if (a) atomicAdd(&counters[0], a);
    if (b) atomicAdd(&counters[1], b);
}

// Load 4 bools at element index idx (multiple of 4) and pack to a 4-bit mask.
template <int FLAG>
__device__ __forceinline__ unsigned pack4(const void* __restrict__ p, int idx) {
    if (FLAG == 1) {
        const uchar4 v = *reinterpret_cast<const uchar4*>(
            reinterpret_cast<const unsigned char*>(p) + idx);
        return (v.x ? 1u : 0u) | (v.y ? 2u : 0u) | (v.z ? 4u : 0u) | (v.w ? 8u : 0u);
    } else if (FLAG == 0) {
        const int4 v = *(reinterpret_cast<const int4*>(
            reinterpret_cast<const int*>(p) + idx));
        return (v.x ? 1u : 0u) | (v.y ? 2u : 0u) | (v.z ? 4u : 0u) | (v.w ? 8u : 0u);
    } else {
        const float4 v = *(reinterpret_cast<const float4*>(
            reinterpret_cast<const float*>(p) + idx));
        return (v.x != 0.f ? 1u : 0u) | (v.y != 0.f ? 2u : 0u) |
               (v.z != 0.f ? 4u : 0u) | (v.w != 0.f ? 8u : 0u);
    }
}

__device__ __forceinline__ float classify(float cur, float prev,
                                          unsigned on, unsigned off) {
    const float d = cur - prev;
    float o = (d == 0.f) ? 127.f : (d > 0.f ? 255.f : 0.f);
    if (on)  o = 255.f;   // on-noise forces 255 ...
    if (off) o = 0.f;     // ... but off-noise wins (matches reference nesting)
    return o;
}

template <int FLAG>
__device__ void neuro_body(const float* __restrict__ tensor,
                           const float* __restrict__ state,
                           const void* __restrict__ on_noise,
                           const void* __restrict__ off_noise,
                           float* __restrict__ out) {
    const int p = (blockIdx.x * BLOCK + threadIdx.x) * PIX;

    // Prefetch + bit-pack ALL noise for this thread's 4 pixels:
    // bit (ni*4 + k) = noise[ni][p + k]. 40 bits per array.
    unsigned long long onb = 0, offb = 0;
#pragma unroll
    for (int ni = 0; ni < N_NOISE; ++ni) {
        onb  |= (unsigned long long)pack4<FLAG>(on_noise,  ni * HW + p) << (ni * 4);
        offb |= (unsigned long long)pack4<FLAG>(off_noise, ni * HW + p) << (ni * 4);
    }

    f4 prev = *reinterpret_cast<const f4*>(state + p);   // zeros in practice
    const float* tp = tensor + p;
    float*       op = out + p;

    int ni = 1;                                          // cnt % N_NOISE at t=0
#pragma unroll 8
    for (int t = 0; t < T_FRAMES; ++t) {
        const f4 cur = __builtin_nontemporal_load(reinterpret_cast<const f4*>(tp));
        const unsigned mon  = (unsigned)(onb  >> (ni * 4)) & 0xFu;
        const unsigned moff = (unsigned)(offb >> (ni * 4)) & 0xFu;

        f4 o;
        o.x = classify(cur.x, prev.x, mon & 1u, moff & 1u);
        o.y = classify(cur.y, prev.y, mon & 2u, moff & 2u);
        o.z = classify(cur.z, prev.z, mon & 4u, moff & 4u);
        o.w = classify(cur.w, prev.w, mon & 8u, moff & 8u);

        __builtin_nontemporal_store(o, reinterpret_cast<f4*>(op));
        prev = cur;
        tp += HW;
        op += HW;
        ni = (ni == N_NOISE - 1) ? 0 : ni + 1;           // uniform (scalar) update
    }
}

__global__ __launch_bounds__(BLOCK)
void neuro_kernel(const float* __restrict__ tensor,
                  const float* __restrict__ state,
                  const void* __restrict__ on_noise,
                  const void* __restrict__ off_noise,
                  float* __restrict__ out,
                  const unsigned int* __restrict__ counters) {
    const unsigned a = counters[0], b = counters[1];
    const int flag = (b == 0u) ? 0 : ((a == 0u) ? 2 : 1);   // wave-uniform
    if (flag == 1)      neuro_body<1>(tensor, state, on_noise, off_noise, out);
    else if (flag == 0) neuro_body<0>(tensor, state, on_noise, off_noise, out);
    else                neuro_body<2>(tensor, state, on_noise, off_noise, out);
}

extern "C" void kernel_launch(void* const* d_in, const int* in_sizes, int n_in,
                              void* d_out, int out_size, void* d_ws, size_t ws_size,
                              hipStream_t stream) {
    const float* tensor   = (const float*)d_in[0];   // (T,H,W) f32
    const float* state    = (const float*)d_in[1];   // (H,W) f32
    // d_in[2] = timesurface (H,W) f32 — provably unused (refractory is a no-op)
    const void*  on_noise  = d_in[3];                // (N_NOISE,H,W) bool
    const void*  off_noise = d_in[4];                // (N_NOISE,H,W) bool
    float* out = (float*)d_out;                      // (T,H,W) f32
    unsigned int* counters = (unsigned int*)d_ws;    // [a, b]

    hipMemsetAsync(counters, 0, 2 * sizeof(unsigned int), stream);

    detect_noise_dtype<<<DET_BLOCKS, 256, 0, stream>>>(
        (const uint4*)on_noise, counters);

    neuro_kernel<<<NBLOCKS, BLOCK, 0, stream>>>(
        tensor, state, on_noise, off_noise, out, counters);
}